// Round 9
// baseline (856.233 us; speedup 1.0000x reference)
//
#include <hip/hip_runtime.h>
#include <hip/hip_bf16.h>

typedef __attribute__((ext_vector_type(8))) short short8;
typedef __attribute__((ext_vector_type(4))) short short4v;
typedef __attribute__((ext_vector_type(4))) float floatx4;
typedef __attribute__((ext_vector_type(4))) unsigned int uintx4;

static __device__ __forceinline__ short bf16bits(float f) {
    __hip_bfloat16 h = __float2bfloat16(f);
    return __builtin_bit_cast(short, h);
}

static __device__ __forceinline__ unsigned int cvtpk(float lo, float hi) {
    unsigned int r;
    asm("v_cvt_pk_bf16_f32 %0, %1, %2" : "=v"(r) : "v"(lo), "v"(hi));
    return r;
}

#define GLDS(g, l) __builtin_amdgcn_global_load_lds( \
    (const __attribute__((address_space(1))) void*)(g), \
    (__attribute__((address_space(3))) void*)(l), 16, 0, 0)

// ---------------------------------------------------------------------------
// fp32 -> bf16 bulk convert. Thread i handles 8 elems.
// ---------------------------------------------------------------------------
__global__ __launch_bounds__(256) void cvt_bf16(
    const float* __restrict__ src, __hip_bfloat16* __restrict__ dst)
{
    size_t i = ((size_t)blockIdx.x * 256 + threadIdx.x) * 8;
    floatx4 f0 = *(const floatx4*)(src + i);
    floatx4 f1 = *(const floatx4*)(src + i + 4);
    short8 s;
#pragma unroll
    for (int j = 0; j < 4; j++) { s[j] = bf16bits(f0[j]); s[j + 4] = bf16bits(f1[j]); }
    *(short8*)((short*)dst + i) = s;
}

// ---------------------------------------------------------------------------
// DBUF GEMM (r8-proven structure, templated tile): C[M,N] = A[M,K]*W[N,K]^T,
// bf16 in, fp32 acc. BK=64, 8 waves (2Mx4N), BM+BN=512 -> 8 GLDS/thread and
// 128 KB LDS for any (BM,BN). Per K-tile: ONE __syncthreads() (vmcnt(0)
// drain + sync) -> issue all 8 GLDS for tile t+1 into freed buffer -> full
// tile-t compute hides the load latency (r8: ~4.75 TF/CU at 256x256).
// Tile choice per GEMM makes gridsize a multiple of 256 (no tail rounds):
//   gemm1 4096x6144: BM=128,BN=384 -> 512 blocks = exactly 2 chip-waves.
//   gemm2 4096x4096: BM=256,BN=256 -> 256 blocks = exactly 1 chip-wave.
// 1D grid + bijective XCD-contiguous tile swizzle (grid%8==0): each XCD's
// L2 serves contiguous B-panel groups (r7 FETCH showed 2.4x panel re-fetch).
// XOR-swizzled LDS rows (physical 16B-block j of row r holds logical
// j^(r&7), pre-swizzled at GLDS source): conflict-free ds_read_b128.
// ---------------------------------------------------------------------------
template<typename CT, int BM, int BN>
__global__ __launch_bounds__(512, 2) void gemm_bt_dbuf(
    const __hip_bfloat16* __restrict__ A,
    const __hip_bfloat16* __restrict__ W,
    CT* __restrict__ C, int M, int N, int K)
{
    constexpr int MF = BM / 2 / 16;     // m-frags per wave (wave-grid 2Mx4N)
    constexpr int NF = BN / 4 / 16;     // n-frags per wave
    constexpr int CA = BM / 8;          // A chunks (8 rows x 1KB each)

    __shared__ alignas(16) short lA[2][BM * 64];
    __shared__ alignas(16) short lB[2][BN * 64];

    const int tid  = threadIdx.x;
    const int wave = tid >> 6;          // 0..7
    const int lane = tid & 63;
    const int quad = lane >> 4;
    const int l16  = lane & 15;

    // XCD-contiguous tile swizzle (bijective: gridDim.x % 8 == 0)
    const int nbx  = M / BM;
    const int q8   = gridDim.x >> 3;
    const int tile = (blockIdx.x & 7) * q8 + (blockIdx.x >> 3);
    const int m0 = (tile % nbx) * BM;
    const int n0 = (tile / nbx) * BN;

    const int wm = (wave >> 2) * (BM / 2);   // wave-row offset
    const int wn = (wave & 3) * (BN / 4);    // wave-col offset

    const int srow = lane >> 3;                    // 0..7 row within chunk
    const int sblk = (lane & 7) ^ srow;            // swizzled source block
    const int scol = sblk * 8;

    const short* Ag = (const short*)A;
    const short* Wg = (const short*)W;

    floatx4 acc[MF][NF];
#pragma unroll
    for (int i = 0; i < MF; i++)
#pragma unroll
        for (int j = 0; j < NF; j++) acc[i][j] = (floatx4)0.0f;

    const int NT = K >> 6;

    // stage full tile t1 (A BMx64 + B BNx64) into buffer dst: 8 GLDS/thread.
    auto stage = [&](int t1, int dst) {
        int k0 = t1 << 6;
#pragma unroll
        for (int p = 0; p < 8; p++) {
            int c = wave * 8 + p;              // combined chunk 0..63
            if (c < CA) {
                int row = c * 8 + srow;
                GLDS(Ag + (size_t)(m0 + row) * K + k0 + scol, &lA[dst][c * 512]);
            } else {
                int cb  = c - CA;
                int row = cb * 8 + srow;
                GLDS(Wg + (size_t)(n0 + row) * K + k0 + scol, &lB[dst][cb * 512]);
            }
        }
    };

    stage(0, 0);

    int cur = 0;
    for (int t = 0; t < NT; t++) {
        __syncthreads();                 // vmcnt(0)+barrier: tile t staged,
                                         // buf cur^1 fully consumed (tile t-1)
        if (t + 1 < NT) stage(t + 1, cur ^ 1);   // overlaps ALL of tile t

#pragma unroll
        for (int kk = 0; kk < 2; kk++) {
            const int pb = ((kk * 4 + quad) ^ (l16 & 7)) * 8;
            short8 bf[NF], af[MF];
#pragma unroll
            for (int j = 0; j < NF; j++)
                bf[j] = *(const short8*)(&lB[cur][(wn + j * 16 + l16) * 64 + pb]);
#pragma unroll
            for (int i = 0; i < MF; i++)
                af[i] = *(const short8*)(&lA[cur][(wm + i * 16 + l16) * 64 + pb]);
            __builtin_amdgcn_s_setprio(1);
#pragma unroll
            for (int i = 0; i < MF; i++)
#pragma unroll
                for (int j = 0; j < NF; j++)
                    acc[i][j] = __builtin_amdgcn_mfma_f32_16x16x32_bf16(
                        af[i], bf[j], acc[i][j], 0, 0, 0);
            __builtin_amdgcn_s_setprio(0);
        }
        cur ^= 1;
    }

    // epilogue
#pragma unroll
    for (int i = 0; i < MF; i++)
#pragma unroll
        for (int j = 0; j < NF; j++) {
            int gm = m0 + wm + i * 16 + quad * 4;
            int gn = n0 + wn + j * 16 + l16;
#pragma unroll
            for (int r = 0; r < 4; r++) {
                float v = acc[i][j][r];
                if constexpr (sizeof(CT) == 2)
                    C[(size_t)(gm + r) * N + gn] = (CT)__float2bfloat16(v);
                else
                    C[(size_t)(gm + r) * N + gn] = (CT)v;
            }
        }
}

// ---------------------------------------------------------------------------
// FALLBACK GEMM — used only if ws too small for bf16 copies.
// ---------------------------------------------------------------------------
template<bool AF32, typename CT>
__global__ __launch_bounds__(256) void gemm_bt_slow(
    const void* __restrict__ A,
    const float* __restrict__ Wf,
    CT* __restrict__ C, int M, int N, int K)
{
    __shared__ alignas(16) short lA[128 * 72];
    __shared__ alignas(16) short lB[128 * 72];

    const int tid  = threadIdx.x;
    const int wave = tid >> 6;
    const int lane = tid & 63;
    const int quad = lane >> 4;
    const int l16  = lane & 15;

    const int m0 = blockIdx.x * 128;
    const int n0 = blockIdx.y * 128;
    const int wm = (wave & 1) * 64;
    const int wn = (wave >> 1) * 64;

    floatx4 acc[4][4];
#pragma unroll
    for (int i = 0; i < 4; i++)
#pragma unroll
        for (int j = 0; j < 4; j++) acc[i][j] = (floatx4)0.0f;

    const short* Ab = (const short*)A;
    const float* Af = (const float*)A;

    for (int k0 = 0; k0 < K; k0 += 64) {
        __syncthreads();
#pragma unroll
        for (int i = 0; i < 4; i++) {
            int chunk = tid + i * 256;
            int row = chunk >> 3;
            int cc  = chunk & 7;
            if (AF32) {
                const float* src = Af + (size_t)(m0 + row) * K + k0 + cc * 8;
                floatx4 f0 = *(const floatx4*)(src);
                floatx4 f1 = *(const floatx4*)(src + 4);
                short8 s;
#pragma unroll
                for (int j = 0; j < 4; j++) { s[j] = bf16bits(f0[j]); s[j + 4] = bf16bits(f1[j]); }
                *(short8*)(&lA[row * 72 + cc * 8]) = s;
            } else {
                *(short8*)(&lA[row * 72 + cc * 8]) =
                    *(const short8*)(Ab + (size_t)(m0 + row) * K + k0 + cc * 8);
            }
            const float* src = Wf + (size_t)(n0 + row) * K + k0 + cc * 8;
            floatx4 f0 = *(const floatx4*)(src);
            floatx4 f1 = *(const floatx4*)(src + 4);
            short8 s;
#pragma unroll
            for (int j = 0; j < 4; j++) { s[j] = bf16bits(f0[j]); s[j + 4] = bf16bits(f1[j]); }
            *(short8*)(&lB[row * 72 + cc * 8]) = s;
        }
        __syncthreads();
#pragma unroll
        for (int kk = 0; kk < 64; kk += 32) {
            short8 af[4], bf[4];
#pragma unroll
            for (int i = 0; i < 4; i++)
                af[i] = *(const short8*)(&lA[(wm + i * 16 + l16) * 72 + kk + quad * 8]);
#pragma unroll
            for (int j = 0; j < 4; j++)
                bf[j] = *(const short8*)(&lB[(wn + j * 16 + l16) * 72 + kk + quad * 8]);
#pragma unroll
            for (int i = 0; i < 4; i++)
#pragma unroll
                for (int j = 0; j < 4; j++)
                    acc[i][j] = __builtin_amdgcn_mfma_f32_16x16x32_bf16(
                        af[i], bf[j], acc[i][j], 0, 0, 0);
        }
    }
#pragma unroll
    for (int i = 0; i < 4; i++)
#pragma unroll
        for (int j = 0; j < 4; j++) {
            int gm = m0 + wm + i * 16 + quad * 4;
            int gn = n0 + wn + j * 16 + l16;
#pragma unroll
            for (int r = 0; r < 4; r++) {
                float v = acc[i][j][r];
                if constexpr (sizeof(CT) == 2)
                    C[(size_t)(gm + r) * N + gn] = (CT)__float2bfloat16(v);
                else
                    C[(size_t)(gm + r) * N + gn] = (CT)v;
            }
        }
}

// ---------------------------------------------------------------------------
// RoPE + RMSNorm in place on bf16 qkv (fp32 cos/sin/weights).
// ---------------------------------------------------------------------------
__global__ __launch_bounds__(256) void rope_norm(
    __hip_bfloat16* __restrict__ qkv,
    const float* __restrict__ cosb,
    const float* __restrict__ sinb,
    const float* __restrict__ qw,
    const float* __restrict__ kw)
{
    int wid  = blockIdx.x * 4 + (threadIdx.x >> 6);
    int lane = threadIdx.x & 63;
    int token = wid / 40;
    int idx   = wid % 40;
    int s = token & 2047;

    int off;
    const float* w;
    if (idx < 32) { off = (idx >> 2) * 768 + (idx & 3) * 128; w = qw; }
    else          { off = (idx - 32) * 768 + 512;             w = kw; }

    short* p = (short*)(qkv + (size_t)token * 6144 + off);
    int d = lane * 2;                              // dims d, d+1

    unsigned int pv = *(const unsigned int*)(p + d);
    float x0 = __builtin_bit_cast(float, pv << 16);
    float x1 = __builtin_bit_cast(float, pv & 0xffff0000u);

    float ox0 = __shfl_xor(x0, 32, 64);            // partner dims d +/- 64
    float ox1 = __shfl_xor(x1, 32, 64);

    float2 cv = *(const float2*)(cosb + s * 128 + d);
    float2 sv = *(const float2*)(sinb + s * 128 + d);
    float sgn = (lane < 32) ? -1.0f : 1.0f;        // d<64: y = x*c - x[d+64]*s
    float y0 = fmaf(sgn * ox0, sv.x, x0 * cv.x);
    float y1 = fmaf(sgn * ox1, sv.y, x1 * cv.y);

    float ss = y0 * y0 + y1 * y1;
#pragma unroll
    for (int m = 1; m < 64; m <<= 1) ss += __shfl_xor(ss, m, 64);
    float r = rsqrtf(ss * (1.0f / 128.0f) + 1e-5f);

    float2 wv = *(const float2*)(w + d);
    unsigned int out = (unsigned int)(unsigned short)bf16bits(y0 * r * wv.x)
                     | ((unsigned int)(unsigned short)bf16bits(y1 * r * wv.y) << 16);
    *(unsigned int*)(p + d) = out;
}

// ---------------------------------------------------------------------------
// V transpose: qkv V-slices -> Vt[b][kvh][d=128][s=2048] (bf16).
// ---------------------------------------------------------------------------
__global__ __launch_bounds__(256) void vtrans(
    const __hip_bfloat16* __restrict__ qkv, __hip_bfloat16* __restrict__ Vt)
{
    __shared__ alignas(16) short lT[64 * 136];

    const int bid   = blockIdx.x;      // 512 = b(2) * kvh(8) * stile(32)
    const int stile = bid & 31;
    const int kvh   = (bid >> 5) & 7;
    const int b     = bid >> 8;
    const int tid   = threadIdx.x;
    const size_t voff = (size_t)kvh * 768 + 640;
    const short* qkvs = (const short*)qkv;

#pragma unroll
    for (int i = 0; i < 4; i++) {
        int chunk = tid + i * 256;
        int t  = chunk >> 4;
        int dc = chunk & 15;
        size_t tok = (size_t)(b * 2048 + stile * 64 + t);
        *(short8*)(&lT[t * 136 + dc * 8]) =
            *(const short8*)(qkvs + tok * 6144 + voff + dc * 8);
    }
    __syncthreads();

    int d  = tid >> 1;
    int kh = (tid & 1) * 32;
    short* out = (short*)Vt + ((size_t)((b * 8 + kvh) * 128 + d)) * 2048
               + stile * 64 + kh;
#pragma unroll
    for (int jb = 0; jb < 4; jb++) {
        short8 s;
#pragma unroll
        for (int j = 0; j < 8; j++) s[j] = lT[(kh + jb * 8 + j) * 136 + d];
        *(short8*)(out + jb * 8) = s;
    }
}

// ---------------------------------------------------------------------------
// Flash attention (GQA). Block = (b, h, 128 q-rows), 4 waves x 32 q-rows.
// SWAPPED-operand QK^T -> S^T; P in-register (cvt_pk + shfl gather);
// PV transposed: O^T = mfma(V^T-frag, P^T-frag). Double-buffered K/V,
// XOR-swizzled LDS, XCD-contiguous blocks, exp2 softmax, defer-max THR=8.
// ---------------------------------------------------------------------------
__global__ __launch_bounds__(256, 2) void attn_kernel(
    const __hip_bfloat16* __restrict__ qkv,
    const __hip_bfloat16* __restrict__ Vt,
    __hip_bfloat16* __restrict__ attn_out)
{
    __shared__ alignas(16) short lK[2][64 * 128];
    __shared__ alignas(16) short lVt[2][128 * 64];

    const int bid0 = blockIdx.x;            // 1024 = b(2) * h(32) * qt(16)
    const int bid  = (bid0 & 7) * 128 + (bid0 >> 3);   // XCD-contiguous
    const int qt   = bid & 15;
    const int h    = (bid >> 4) & 31;
    const int b    = bid >> 9;
    const int kvh  = h >> 2;
    const int lane = threadIdx.x & 63;
    const int wave = threadIdx.x >> 6;
    const int quad = lane >> 4;
    const int l16  = lane & 15;

    const size_t qoff = (size_t)kvh * 768 + (size_t)(h & 3) * 128;
    const size_t koff = (size_t)kvh * 768 + 512;
    const short* qkvs = (const short*)qkv;
    const short* Vts  = (const short*)Vt + ((size_t)(b * 8 + kvh) * 128) * 2048;

    // Q fragments: 2 m-tiles x 4 k-steps. B-frag of Q: lane l16 = q-col.
    short8 qf[2][4];
#pragma unroll
    for (int t = 0; t < 2; t++) {
        const int qrow = qt * 128 + wave * 32 + t * 16 + l16;
        const size_t qtok = (size_t)(b * 2048 + qrow);
#pragma unroll
        for (int kk = 0; kk < 4; kk++)
            qf[t][kk] = *(const short8*)(qkvs + qtok * 6144 + qoff + kk * 32 + quad * 8);
    }

    // O^T accumulator: rows d = n*16 + quad*4 + r, col q = l16.
    floatx4 o[2][8];
#pragma unroll
    for (int t = 0; t < 2; t++)
#pragma unroll
        for (int n = 0; n < 8; n++) o[t][n] = (floatx4)0.0f;
    float mrow[2] = { -3.0e4f, -3.0e4f };
    float lsum[2] = { 0.0f, 0.0f };

    // softmax in log2 domain: 2^(s*scale2) == e^(s*scale)
    const float scale2 = 0.08838834764831845f * 1.4426950408889634f;
    const float THR2   = 11.5418f;            // 8 nats in log2

    // staging lane coords (swizzled source blocks)
    const int k_row = lane >> 4;                       // 0..3 key in chunk
    const int v_row = lane >> 3;                       // 0..7 dim in chunk
    const int v_blk = (lane & 7) ^ v_row;              // lVt swizzle (row&7 = v_row)

    // P^T gather source lanes
    const int srcA = l16 + ((lane & 16) << 1);         // l16 + 32*(quad&1)
    const int srcB = srcA + 16;
    const bool hi2 = (quad >> 1) != 0;

    // prologue: stage tile 0 into buffer 0
#pragma unroll
    for (int i = 0; i < 4; i++) {
        int c = wave * 4 + i;
        int k_blk = (lane & 15) ^ ((c * 4 + k_row) & 15);
        size_t tok = (size_t)(b * 2048 + c * 4 + k_row);
        GLDS(qkvs + tok * 6144 + koff + k_blk * 8, &lK[0][c * 512]);
        int d = c * 8 + v_row;
        GLDS(Vts + (size_t)d * 2048 + v_blk * 8, &lVt[0][c * 512]);
    }

    int cur = 0;
    for (int kt = 0; kt < 32; kt++) {
        __syncthreads();   // staged tile kt complete; buf cur^1 free

        if (kt < 31) {
            short* nK = &lK[cur ^ 1][0];
            short* nV = &lVt[cur ^ 1][0];
#pragma unroll
            for (int i = 0; i < 4; i++) {
                int c = wave * 4 + i;
                int k_blk = (lane & 15) ^ ((c * 4 + k_row) & 15);
                size_t tok = (size_t)(b * 2048 + (kt + 1) * 64 + c * 4 + k_row);
                GLDS(qkvs + tok * 6144 + koff + k_blk * 8, nK + c * 512);
                int d = c * 8 + v_row;
                GLDS(Vts + (size_t)d * 2048 + (kt + 1) * 64 + v_blk * 8, nV + c * 512);
            }
        }

        const short* lKc = &lK[cur][0];
        const short* lVc = &lVt[cur][0];

        // S^T = (Q K^T)^T : sc[t][n][r] = S[key = n*16+quad*4+r][q = l16]
        floatx4 sc[2][4];
#pragma unroll
        for (int t = 0; t < 2; t++)
#pragma unroll
            for (int n = 0; n < 4; n++) sc[t][n] = (floatx4)0.0f;
#pragma unroll
        for (int kk = 0; kk < 4; kk++) {
#pragma unroll
            for (int n = 0; n < 4; n++) {
                short8 kf = *(const short8*)(
                    &lKc[(n * 16 + l16) * 128 + (((kk * 4 + quad) ^ l16)) * 8]);
                sc[0][n] = __builtin_amdgcn_mfma_f32_16x16x32_bf16(kf, qf[0][kk], sc[0][n], 0, 0, 0);
                sc[1][n] = __builtin_amdgcn_mfma_f32_16x16x32_bf16(kf, qf[1][kk], sc[1][n], 0, 0, 0);
            }
        }

        // softmax (log2 domain) + in-register P^T B-fragment build
        short8 pb[2][2];
#pragma unroll
        for (int t = 0; t < 2; t++) {
            // lane-local raw max over 16 regs, then cross-quad reduce
            float ma = fmaxf(fmaxf(sc[t][0][0], sc[t][0][1]), fmaxf(sc[t][0][2], sc[t][0][3]));
            float mb = fmaxf(fmaxf(sc[t][1][0], sc[t][1][1]), fmaxf(sc[t][1][2], sc[t][1][3]));
            float mc = fmaxf(fmaxf(sc[t][2][0], sc[t][2][1]), fmaxf(sc[t][2][2], sc[t][2][3]));
            float md = fmaxf(fmaxf(sc[t][3][0], sc[t][3][1]), fmaxf(sc[t][3][2], sc[t][3][3]));
            float mr = fmaxf(fmaxf(ma, mb), fmaxf(mc, md));
            mr = fmaxf(mr, __shfl_xor(mr, 16, 64));
            mr = fmaxf(mr, __shfl_xor(mr, 32, 64));
            float mx = mr * scale2;

            int grown = mx > mrow[t] + THR2;
            if (__any(grown)) {
                float mn = fmaxf(mrow[t], mx);
                float alpha = exp2f(mrow[t] - mn);
                mrow[t] = mn;
                lsum[t] *= alpha;
#pragma unroll
                for (int n = 0; n < 8; n++)
#pragma unroll
                    for (int r = 0; r < 4; r++) o[t][n][r] *= alpha;
            }

            const float nm = -mrow[t];
            float ps = 0.0f;
            unsigned int pk[4][2];
#pragma unroll
            for (int n = 0; n < 4; n++) {
#pragma unroll
                for (int r = 0; r < 4; r++) {
                    float pv = exp2f(fmaf(sc[t][n][r], scale2, nm));
                    sc[t][n][r] = pv;
                    ps += pv;
                }
                pk[n][0] = cvtpk(sc[t][n][0], sc[t][n][1]);
                pk[n][1] = cvtpk(sc[t][n][2], sc[t][n][3]);
            }
            lsum[t] += ps;

            // gather P^T B-frags: dest (l16,quad) kk2 needs keys kk2*32+quad*8+j
#pragma unroll
            for (int kk2 = 0; kk2 < 2; kk2++) {
                unsigned int a0 = __shfl(pk[2 * kk2][0],     srcA, 64);
                unsigned int a1 = __shfl(pk[2 * kk2 + 1][0], srcA, 64);
                unsigned int a2 = __shfl(pk[2 * kk2][1],     srcA, 64);
                unsigned int a3 = __shfl(pk[2 * kk2 + 1][1], srcA, 64);
                unsigned int c0 = __shfl(pk[2 * kk2][0],     srcB, 64);
                unsigned int c1 = __shfl(pk[2 * kk2 + 1][0], srcB, 64);
                unsigned int c2 = __shfl(pk[2 * kk2][1],     srcB, 64);
                unsigned int c3 = __shfl(pk[2 * kk2 + 1][1], srcB, 64);
                uintx4 u;
                u[0] = hi2 ? a1 : a0;
                u[1] = hi2 ? a3 : a2;
                u[2] = hi2 ? c1 : c0;
                u[3] = hi2 ? c3 : c2;
                pb[t][kk2] = __builtin_bit_cast(short8, u);
            }
        }

        // O^T += V^T * P^T
#pragma unroll
        for (int kk2 = 0; kk2 < 2; kk2++) {
            const int pbv = ((kk2 * 4 + quad) ^ (l16 & 7)) * 8;
#pragma unroll
            for (int n = 0; n < 8; n++) {
                short8 vf = *(const short8*)(&lVc[(n * 16 + l16) * 64 + pbv]);
                o[0][n] = __builtin_amdgcn_mfma_f32_16x16x32_bf16(vf, pb[0][kk2], o[0][n], 0, 0, 0);
                o[1][n] = __builtin_amdgcn_mfma_f32_16x16x32_bf16(vf, pb[1][kk2], o[1][n], 0, 0, 0);
            }
        }

        cur ^= 1;
    }

    // final row-sum reduce across quads (once) -> reciprocal
    float inv[2];
#pragma unroll
    for (int t = 0; t < 2; t++) {
        float s = lsum[t];
        s += __shfl_xor(s, 16, 64);
        s += __shfl_xor(s, 32, 64);
        inv[t] = 1.0f / s;
    }

    // O^T epilogue: lane l16 = q (token), rows d = n*16 + quad*4 + r
#pragma unroll
    for (int t = 0; t < 2; t++) {
        const int row = qt * 128 + wave * 32 + t * 16 + l16;
        const size_t tok = (size_t)(b * 2048 + row);
        short* outp = (short*)attn_out + tok * 4096 + h * 128 + quad * 4;
#pragma unroll
        for (int n = 0; n < 8; n++) {
            short4v s4;
#pragma unroll
            for (int r = 0; r < 4; r++) s4[r] = bf16bits(o[t][n][r] * inv[t]);
            *(short4v*)(outp + n * 16) = s4;
        }
    }
}

// ---------------------------------------------------------------------------
extern "C" void kernel_launch(void* const* d_in, const int* in_sizes, int n_in,
                              void* d_out, int out_size, void* d_ws, size_t ws_size,
                              hipStream_t stream) {
    const float* hidden = (const float*)d_in[0];
    const float* cosb   = (const float*)d_in[1];
    const float* sinb   = (const float*)d_in[2];
    const float* w_qkv  = (const float*)d_in[3];
    const float* w_o    = (const float*)d_in[4];
    const float* qw     = (const float*)d_in[5];
    const float* kw     = (const float*)d_in[6];

    char* ws = (char*)d_ws;
    __hip_bfloat16* qkv    = (__hip_bfloat16*)ws;                     // 50.33 MB
    __hip_bfloat16* attn_o = (__hip_bfloat16*)(ws + 50331648);        // 33.55 MB
    __hip_bfloat16* hb  = (__hip_bfloat16*)(ws + 83886080);           // 33.55 MB
    __hip_bfloat16* wb1 = (__hip_bfloat16*)(ws + 117440512);          // 50.33 MB
    __hip_bfloat16* wb2 = (__hip_bfloat16*)(ws + 167772160);          // 33.55 MB
    const size_t WS_FAST = 201326592;                                  // 192 MiB

    __hip_bfloat16* Vt = (__hip_bfloat16*)d_out;   // 8.4 MB scratch, dead before gemm2
    float* outp        = (float*)d_out;

    const bool fast = (ws_size >= WS_FAST);

    if (fast) {
        cvt_bf16<<<16777216 / 8 / 256, 256, 0, stream>>>(hidden, hb);
        cvt_bf16<<<25165824 / 8 / 256, 256, 0, stream>>>(w_qkv, wb1);
        cvt_bf16<<<16777216 / 8 / 256, 256, 0, stream>>>(w_o, wb2);
        // 4096x6144: BM=128,BN=384 -> 32x16 = 512 blocks = 2 exact chip-waves
        gemm_bt_dbuf<__hip_bfloat16, 128, 384><<<512, 512, 0, stream>>>(
            hb, wb1, qkv, 4096, 6144, 4096);
    } else {
        dim3 g1(32, 48);
        gemm_bt_slow<true, __hip_bfloat16><<<g1, 256, 0, stream>>>(hidden, w_qkv, qkv, 4096, 6144, 4096);
    }

    rope_norm<<<40960, 256, 0, stream>>>(qkv, cosb, sinb, qw, kw);

    vtrans<<<512, 256, 0, stream>>>(qkv, Vt);

    attn_kernel<<<1024, 256, 0, stream>>>(qkv, Vt, attn_o);

    if (fast) {
        // 4096x4096: BM=256,BN=256 -> 16x16 = 256 blocks = 1 exact chip-wave
        gemm_bt_dbuf<float, 256, 256><<<256, 512, 0, stream>>>(
            attn_o, wb2, outp, 4096, 4096, 4096);
    } else {
        dim3 g2(32, 32);
        gemm_bt_slow<false, float><<<g2, 256, 0, stream>>>(attn_o, w_o, outp, 4096, 4096, 4096);
    }
}

// Round 12
// 827.728 us; speedup vs baseline: 1.0344x; 1.0344x over previous
//
#include <hip/hip_runtime.h>
#include <hip/hip_bf16.h>

typedef __attribute__((ext_vector_type(8))) short short8;
typedef __attribute__((ext_vector_type(4))) short short4v;
typedef __attribute__((ext_vector_type(4))) float floatx4;
typedef __attribute__((ext_vector_type(4))) unsigned int uintx4;

static __device__ __forceinline__ short bf16bits(float f) {
    __hip_bfloat16 h = __float2bfloat16(f);
    return __builtin_bit_cast(short, h);
}

static __device__ __forceinline__ unsigned int cvtpk(float lo, float hi) {
    unsigned int r;
    asm("v_cvt_pk_bf16_f32 %0, %1, %2" : "=v"(r) : "v"(lo), "v"(hi));
    return r;
}

#define GLDS(g, l) __builtin_amdgcn_global_load_lds( \
    (const __attribute__((address_space(1))) void*)(g), \
    (__attribute__((address_space(3))) void*)(l), 16, 0, 0)

// ---------------------------------------------------------------------------
// fp32 -> bf16 bulk convert. Thread i handles 8 elems.
// ---------------------------------------------------------------------------
__global__ __launch_bounds__(256) void cvt_bf16(
    const float* __restrict__ src, __hip_bfloat16* __restrict__ dst)
{
    size_t i = ((size_t)blockIdx.x * 256 + threadIdx.x) * 8;
    floatx4 f0 = *(const floatx4*)(src + i);
    floatx4 f1 = *(const floatx4*)(src + i + 4);
    short8 s;
#pragma unroll
    for (int j = 0; j < 4; j++) { s[j] = bf16bits(f0[j]); s[j + 4] = bf16bits(f1[j]); }
    *(short8*)((short*)dst + i) = s;
}

// ---------------------------------------------------------------------------
// DBUF GEMM (r8-proven structure, generalized): C[M,N] = A[M,K]*W[N,K]^T,
// bf16 in, fp32 acc. BK=64. TPB/64 waves in a WRxWC grid. Per K-tile: ONE
// __syncthreads() (vmcnt(0) drain + sync) -> issue all GLDS for tile t+1
// into freed buffer -> full tile-t compute hides load latency.
// r9 lesson: at 128KB LDS (1 block/CU) a barrier stall eats full L2/HBM miss
// latency with nothing else to run. gemm1 therefore uses 128x128 @ 64KB LDS
// -> 2 blocks/CU: cross-block overlap absorbs the stall. gemm2 keeps the
// proven 256x256 @ 8 waves (r8: ~1215 TF).
// 1D grid + bijective XCD-contiguous tile swizzle (grid%8==0).
// XOR-swizzled LDS rows (block j of row r holds logical j^(r&7), staged
// pre-swizzled via GLDS source addr): conflict-free ds_read_b128.
// ---------------------------------------------------------------------------
template<typename CT, int BM, int BN, int TPB, int WC>
__global__ __launch_bounds__(TPB, 2) void gemm_bt_dbuf(
    const __hip_bfloat16* __restrict__ A,
    const __hip_bfloat16* __restrict__ W,
    CT* __restrict__ C, int M, int N, int K)
{
    constexpr int WAVES = TPB / 64;
    constexpr int WR  = WAVES / WC;       // wave-rows
    constexpr int MF  = BM / WR / 16;     // m-frags per wave
    constexpr int NF  = BN / WC / 16;     // n-frags per wave
    constexpr int CA  = BM / 8;           // A chunks (8 rows x 1KB)
    constexpr int CPW = (BM + BN) / 8 / WAVES;  // chunks per wave

    __shared__ alignas(16) short lA[2][BM * 64];
    __shared__ alignas(16) short lB[2][BN * 64];

    const int tid  = threadIdx.x;
    const int wave = tid >> 6;
    const int lane = tid & 63;
    const int quad = lane >> 4;
    const int l16  = lane & 15;

    // XCD-contiguous tile swizzle (bijective: gridDim.x % 8 == 0)
    const int nbx  = M / BM;
    const int q8   = gridDim.x >> 3;
    const int tile = (blockIdx.x & 7) * q8 + (blockIdx.x >> 3);
    const int m0 = (tile % nbx) * BM;
    const int n0 = (tile / nbx) * BN;

    const int wm = (wave / WC) * (BM / WR);
    const int wn = (wave % WC) * (BN / WC);

    const int srow = lane >> 3;                    // 0..7 row within chunk
    const int sblk = (lane & 7) ^ srow;            // swizzled source block
    const int scol = sblk * 8;

    const short* Ag = (const short*)A;
    const short* Wg = (const short*)W;

    floatx4 acc[MF][NF];
#pragma unroll
    for (int i = 0; i < MF; i++)
#pragma unroll
        for (int j = 0; j < NF; j++) acc[i][j] = (floatx4)0.0f;

    const int NT = K >> 6;

    // stage full tile t1 (A BMx64 + B BNx64) into buffer dst: CPW GLDS/thread
    auto stage = [&](int t1, int dst) {
        int k0 = t1 << 6;
#pragma unroll
        for (int p = 0; p < CPW; p++) {
            int c = wave * CPW + p;            // combined chunk
            if (c < CA) {
                int row = c * 8 + srow;
                GLDS(Ag + (size_t)(m0 + row) * K + k0 + scol, &lA[dst][c * 512]);
            } else {
                int cb  = c - CA;
                int row = cb * 8 + srow;
                GLDS(Wg + (size_t)(n0 + row) * K + k0 + scol, &lB[dst][cb * 512]);
            }
        }
    };

    stage(0, 0);

    int cur = 0;
    for (int t = 0; t < NT; t++) {
        __syncthreads();                 // vmcnt(0)+barrier: tile t staged,
                                         // buf cur^1 fully consumed (tile t-1)
        if (t + 1 < NT) stage(t + 1, cur ^ 1);   // overlaps ALL of tile t

#pragma unroll
        for (int kk = 0; kk < 2; kk++) {
            const int pb = ((kk * 4 + quad) ^ (l16 & 7)) * 8;
            short8 bf[NF], af[MF];
#pragma unroll
            for (int j = 0; j < NF; j++)
                bf[j] = *(const short8*)(&lB[cur][(wn + j * 16 + l16) * 64 + pb]);
#pragma unroll
            for (int i = 0; i < MF; i++)
                af[i] = *(const short8*)(&lA[cur][(wm + i * 16 + l16) * 64 + pb]);
            __builtin_amdgcn_s_setprio(1);
#pragma unroll
            for (int i = 0; i < MF; i++)
#pragma unroll
                for (int j = 0; j < NF; j++)
                    acc[i][j] = __builtin_amdgcn_mfma_f32_16x16x32_bf16(
                        af[i], bf[j], acc[i][j], 0, 0, 0);
            __builtin_amdgcn_s_setprio(0);
        }
        cur ^= 1;
    }

    // epilogue
#pragma unroll
    for (int i = 0; i < MF; i++)
#pragma unroll
        for (int j = 0; j < NF; j++) {
            int gm = m0 + wm + i * 16 + quad * 4;
            int gn = n0 + wn + j * 16 + l16;
#pragma unroll
            for (int r = 0; r < 4; r++) {
                float v = acc[i][j][r];
                if constexpr (sizeof(CT) == 2)
                    C[(size_t)(gm + r) * N + gn] = (CT)__float2bfloat16(v);
                else
                    C[(size_t)(gm + r) * N + gn] = (CT)v;
            }
        }
}

// ---------------------------------------------------------------------------
// FALLBACK GEMM — used only if ws too small for bf16 copies.
// ---------------------------------------------------------------------------
template<bool AF32, typename CT>
__global__ __launch_bounds__(256) void gemm_bt_slow(
    const void* __restrict__ A,
    const float* __restrict__ Wf,
    CT* __restrict__ C, int M, int N, int K)
{
    __shared__ alignas(16) short lA[128 * 72];
    __shared__ alignas(16) short lB[128 * 72];

    const int tid  = threadIdx.x;
    const int wave = tid >> 6;
    const int lane = tid & 63;
    const int quad = lane >> 4;
    const int l16  = lane & 15;

    const int m0 = blockIdx.x * 128;
    const int n0 = blockIdx.y * 128;
    const int wm = (wave & 1) * 64;
    const int wn = (wave >> 1) * 64;

    floatx4 acc[4][4];
#pragma unroll
    for (int i = 0; i < 4; i++)
#pragma unroll
        for (int j = 0; j < 4; j++) acc[i][j] = (floatx4)0.0f;

    const short* Ab = (const short*)A;
    const float* Af = (const float*)A;

    for (int k0 = 0; k0 < K; k0 += 64) {
        __syncthreads();
#pragma unroll
        for (int i = 0; i < 4; i++) {
            int chunk = tid + i * 256;
            int row = chunk >> 3;
            int cc  = chunk & 7;
            if (AF32) {
                const float* src = Af + (size_t)(m0 + row) * K + k0 + cc * 8;
                floatx4 f0 = *(const floatx4*)(src);
                floatx4 f1 = *(const floatx4*)(src + 4);
                short8 s;
#pragma unroll
                for (int j = 0; j < 4; j++) { s[j] = bf16bits(f0[j]); s[j + 4] = bf16bits(f1[j]); }
                *(short8*)(&lA[row * 72 + cc * 8]) = s;
            } else {
                *(short8*)(&lA[row * 72 + cc * 8]) =
                    *(const short8*)(Ab + (size_t)(m0 + row) * K + k0 + cc * 8);
            }
            const float* src = Wf + (size_t)(n0 + row) * K + k0 + cc * 8;
            floatx4 f0 = *(const floatx4*)(src);
            floatx4 f1 = *(const floatx4*)(src + 4);
            short8 s;
#pragma unroll
            for (int j = 0; j < 4; j++) { s[j] = bf16bits(f0[j]); s[j + 4] = bf16bits(f1[j]); }
            *(short8*)(&lB[row * 72 + cc * 8]) = s;
        }
        __syncthreads();
#pragma unroll
        for (int kk = 0; kk < 64; kk += 32) {
            short8 af[4], bf[4];
#pragma unroll
            for (int i = 0; i < 4; i++)
                af[i] = *(const short8*)(&lA[(wm + i * 16 + l16) * 72 + kk + quad * 8]);
#pragma unroll
            for (int j = 0; j < 4; j++)
                bf[j] = *(const short8*)(&lB[(wn + j * 16 + l16) * 72 + kk + quad * 8]);
#pragma unroll
            for (int i = 0; i < 4; i++)
#pragma unroll
                for (int j = 0; j < 4; j++)
                    acc[i][j] = __builtin_amdgcn_mfma_f32_16x16x32_bf16(
                        af[i], bf[j], acc[i][j], 0, 0, 0);
        }
    }
#pragma unroll
    for (int i = 0; i < 4; i++)
#pragma unroll
        for (int j = 0; j < 4; j++) {
            int gm = m0 + wm + i * 16 + quad * 4;
            int gn = n0 + wn + j * 16 + l16;
#pragma unroll
            for (int r = 0; r < 4; r++) {
                float v = acc[i][j][r];
                if constexpr (sizeof(CT) == 2)
                    C[(size_t)(gm + r) * N + gn] = (CT)__float2bfloat16(v);
                else
                    C[(size_t)(gm + r) * N + gn] = (CT)v;
            }
        }
}

// ---------------------------------------------------------------------------
// RoPE + RMSNorm in place on bf16 qkv (fp32 cos/sin/weights).
// ---------------------------------------------------------------------------
__global__ __launch_bounds__(256) void rope_norm(
    __hip_bfloat16* __restrict__ qkv,
    const float* __restrict__ cosb,
    const float* __restrict__ sinb,
    const float* __restrict__ qw,
    const float* __restrict__ kw)
{
    int wid  = blockIdx.x * 4 + (threadIdx.x >> 6);
    int lane = threadIdx.x & 63;
    int token = wid / 40;
    int idx   = wid % 40;
    int s = token & 2047;

    int off;
    const float* w;
    if (idx < 32) { off = (idx >> 2) * 768 + (idx & 3) * 128; w = qw; }
    else          { off = (idx - 32) * 768 + 512;             w = kw; }

    short* p = (short*)(qkv + (size_t)token * 6144 + off);
    int d = lane * 2;                              // dims d, d+1

    unsigned int pv = *(const unsigned int*)(p + d);
    float x0 = __builtin_bit_cast(float, pv << 16);
    float x1 = __builtin_bit_cast(float, pv & 0xffff0000u);

    float ox0 = __shfl_xor(x0, 32, 64);            // partner dims d +/- 64
    float ox1 = __shfl_xor(x1, 32, 64);

    float2 cv = *(const float2*)(cosb + s * 128 + d);
    float2 sv = *(const float2*)(sinb + s * 128 + d);
    float sgn = (lane < 32) ? -1.0f : 1.0f;        // d<64: y = x*c - x[d+64]*s
    float y0 = fmaf(sgn * ox0, sv.x, x0 * cv.x);
    float y1 = fmaf(sgn * ox1, sv.y, x1 * cv.y);

    float ss = y0 * y0 + y1 * y1;
#pragma unroll
    for (int m = 1; m < 64; m <<= 1) ss += __shfl_xor(ss, m, 64);
    float r = rsqrtf(ss * (1.0f / 128.0f) + 1e-5f);

    float2 wv = *(const float2*)(w + d);
    unsigned int out = (unsigned int)(unsigned short)bf16bits(y0 * r * wv.x)
                     | ((unsigned int)(unsigned short)bf16bits(y1 * r * wv.y) << 16);
    *(unsigned int*)(p + d) = out;
}

// ---------------------------------------------------------------------------
// V transpose: qkv V-slices -> Vt[b][kvh][d=128][s=2048] (bf16).
// ---------------------------------------------------------------------------
__global__ __launch_bounds__(256) void vtrans(
    const __hip_bfloat16* __restrict__ qkv, __hip_bfloat16* __restrict__ Vt)
{
    __shared__ alignas(16) short lT[64 * 136];

    const int bid   = blockIdx.x;      // 512 = b(2) * kvh(8) * stile(32)
    const int stile = bid & 31;
    const int kvh   = (bid >> 5) & 7;
    const int b     = bid >> 8;
    const int tid   = threadIdx.x;
    const size_t voff = (size_t)kvh * 768 + 640;
    const short* qkvs = (const short*)qkv;

#pragma unroll
    for (int i = 0; i < 4; i++) {
        int chunk = tid + i * 256;
        int t  = chunk >> 4;
        int dc = chunk & 15;
        size_t tok = (size_t)(b * 2048 + stile * 64 + t);
        *(short8*)(&lT[t * 136 + dc * 8]) =
            *(const short8*)(qkvs + tok * 6144 + voff + dc * 8);
    }
    __syncthreads();

    int d  = tid >> 1;
    int kh = (tid & 1) * 32;
    short* out = (short*)Vt + ((size_t)((b * 8 + kvh) * 128 + d)) * 2048
               + stile * 64 + kh;
#pragma unroll
    for (int jb = 0; jb < 4; jb++) {
        short8 s;
#pragma unroll
        for (int j = 0; j < 8; j++) s[j] = lT[(kh + jb * 8 + j) * 136 + d];
        *(short8*)(out + jb * 8) = s;
    }
}

// ---------------------------------------------------------------------------
// Flash attention (GQA). Block = (b, h, 128 q-rows), 4 waves x 32 q-rows.
// SWAPPED-operand QK^T -> S^T; P in-register (cvt_pk + shfl gather);
// PV transposed: O^T = mfma(V^T-frag, P^T-frag). Double-buffered K/V,
// XOR-swizzled LDS, XCD-contiguous blocks, exp2 softmax, defer-max THR=8.
// ---------------------------------------------------------------------------
__global__ __launch_bounds__(256, 2) void attn_kernel(
    const __hip_bfloat16* __restrict__ qkv,
    const __hip_bfloat16* __restrict__ Vt,
    __hip_bfloat16* __restrict__ attn_out)
{
    __shared__ alignas(16) short lK[2][64 * 128];
    __shared__ alignas(16) short lVt[2][128 * 64];

    const int bid0 = blockIdx.x;            // 1024 = b(2) * h(32) * qt(16)
    const int bid  = (bid0 & 7) * 128 + (bid0 >> 3);   // XCD-contiguous
    const int qt   = bid & 15;
    const int h    = (bid >> 4) & 31;
    const int b    = bid >> 9;
    const int kvh  = h >> 2;
    const int lane = threadIdx.x & 63;
    const int wave = threadIdx.x >> 6;
    const int quad = lane >> 4;
    const int l16  = lane & 15;

    const size_t qoff = (size_t)kvh * 768 + (size_t)(h & 3) * 128;
    const size_t koff = (size_t)kvh * 768 + 512;
    const short* qkvs = (const short*)qkv;
    const short* Vts  = (const short*)Vt + ((size_t)(b * 8 + kvh) * 128) * 2048;

    // Q fragments: 2 m-tiles x 4 k-steps. B-frag of Q: lane l16 = q-col.
    short8 qf[2][4];
#pragma unroll
    for (int t = 0; t < 2; t++) {
        const int qrow = qt * 128 + wave * 32 + t * 16 + l16;
        const size_t qtok = (size_t)(b * 2048 + qrow);
#pragma unroll
        for (int kk = 0; kk < 4; kk++)
            qf[t][kk] = *(const short8*)(qkvs + qtok * 6144 + qoff + kk * 32 + quad * 8);
    }

    // O^T accumulator: rows d = n*16 + quad*4 + r, col q = l16.
    floatx4 o[2][8];
#pragma unroll
    for (int t = 0; t < 2; t++)
#pragma unroll
        for (int n = 0; n < 8; n++) o[t][n] = (floatx4)0.0f;
    float mrow[2] = { -3.0e4f, -3.0e4f };
    float lsum[2] = { 0.0f, 0.0f };

    // softmax in log2 domain: 2^(s*scale2) == e^(s*scale)
    const float scale2 = 0.08838834764831845f * 1.4426950408889634f;
    const float THR2   = 11.5418f;            // 8 nats in log2

    // staging lane coords (swizzled source blocks)
    const int k_row = lane >> 4;                       // 0..3 key in chunk
    const int v_row = lane >> 3;                       // 0..7 dim in chunk
    const int v_blk = (lane & 7) ^ v_row;              // lVt swizzle (row&7 = v_row)

    // P^T gather source lanes
    const int srcA = l16 + ((lane & 16) << 1);         // l16 + 32*(quad&1)
    const int srcB = srcA + 16;
    const bool hi2 = (quad >> 1) != 0;

    // prologue: stage tile 0 into buffer 0
#pragma unroll
    for (int i = 0; i < 4; i++) {
        int c = wave * 4 + i;
        int k_blk = (lane & 15) ^ ((c * 4 + k_row) & 15);
        size_t tok = (size_t)(b * 2048 + c * 4 + k_row);
        GLDS(qkvs + tok * 6144 + koff + k_blk * 8, &lK[0][c * 512]);
        int d = c * 8 + v_row;
        GLDS(Vts + (size_t)d * 2048 + v_blk * 8, &lVt[0][c * 512]);
    }

    int cur = 0;
    for (int kt = 0; kt < 32; kt++) {
        __syncthreads();   // staged tile kt complete; buf cur^1 free

        if (kt < 31) {
            short* nK = &lK[cur ^ 1][0];
            short* nV = &lVt[cur ^ 1][0];
#pragma unroll
            for (int i = 0; i < 4; i++) {
                int c = wave * 4 + i;
                int k_blk = (lane & 15) ^ ((c * 4 + k_row) & 15);
                size_t tok = (size_t)(b * 2048 + (kt + 1) * 64 + c * 4 + k_row);
                GLDS(qkvs + tok * 6144 + koff + k_blk * 8, nK + c * 512);
                int d = c * 8 + v_row;
                GLDS(Vts + (size_t)d * 2048 + (kt + 1) * 64 + v_blk * 8, nV + c * 512);
            }
        }

        const short* lKc = &lK[cur][0];
        const short* lVc = &lVt[cur][0];

        // S^T = (Q K^T)^T : sc[t][n][r] = S[key = n*16+quad*4+r][q = l16]
        floatx4 sc[2][4];
#pragma unroll
        for (int t = 0; t < 2; t++)
#pragma unroll
            for (int n = 0; n < 4; n++) sc[t][n] = (floatx4)0.0f;
#pragma unroll
        for (int kk = 0; kk < 4; kk++) {
#pragma unroll
            for (int n = 0; n < 4; n++) {
                short8 kf = *(const short8*)(
                    &lKc[(n * 16 + l16) * 128 + (((kk * 4 + quad) ^ l16)) * 8]);
                sc[0][n] = __builtin_amdgcn_mfma_f32_16x16x32_bf16(kf, qf[0][kk], sc[0][n], 0, 0, 0);
                sc[1][n] = __builtin_amdgcn_mfma_f32_16x16x32_bf16(kf, qf[1][kk], sc[1][n], 0, 0, 0);
            }
        }

        // softmax (log2 domain) + in-register P^T B-fragment build
        short8 pb[2][2];
#pragma unroll
        for (int t = 0; t < 2; t++) {
            // lane-local raw max over 16 regs, then cross-quad reduce
            float ma = fmaxf(fmaxf(sc[t][0][0], sc[t][0][1]), fmaxf(sc[t][0][2], sc[t][0][3]));
            float mb = fmaxf(fmaxf(sc[t][1][0], sc[t][1][1]), fmaxf(sc[t][1][2], sc[t][1][3]));
            float mc = fmaxf(fmaxf(sc[t][2][0], sc[t][2][1]), fmaxf(sc[t][2][2], sc[t][2][3]));
            float md = fmaxf(fmaxf(sc[t][3][0], sc[t][3][1]), fmaxf(sc[t][3][2], sc[t][3][3]));
            float mr = fmaxf(fmaxf(ma, mb), fmaxf(mc, md));
            mr = fmaxf(mr, __shfl_xor(mr, 16, 64));
            mr = fmaxf(mr, __shfl_xor(mr, 32, 64));
            float mx = mr * scale2;

            int grown = mx > mrow[t] + THR2;
            if (__any(grown)) {
                float mn = fmaxf(mrow[t], mx);
                float alpha = exp2f(mrow[t] - mn);
                mrow[t] = mn;
                lsum[t] *= alpha;
#pragma unroll
                for (int n = 0; n < 8; n++)
#pragma unroll
                    for (int r = 0; r < 4; r++) o[t][n][r] *= alpha;
            }

            const float nm = -mrow[t];
            float ps = 0.0f;
            unsigned int pk[4][2];
#pragma unroll
            for (int n = 0; n < 4; n++) {
#pragma unroll
                for (int r = 0; r < 4; r++) {
                    float pv = exp2f(fmaf(sc[t][n][r], scale2, nm));
                    sc[t][n][r] = pv;
                    ps += pv;
                }
                pk[n][0] = cvtpk(sc[t][n][0], sc[t][n][1]);
                pk[n][1] = cvtpk(sc[t][n][2], sc[t][n][3]);
            }
            lsum[t] += ps;

            // gather P^T B-frags: dest (l16,quad) kk2 needs keys kk2*32+quad*8+j
#pragma unroll
            for (int kk2 = 0; kk2 < 2; kk2++) {
                unsigned int a0 = __shfl(pk[2 * kk2][0],     srcA, 64);
                unsigned int a1 = __shfl(pk[2 * kk2 + 1][0], srcA, 64);
                unsigned int a2 = __shfl(pk[2 * kk2][1],     srcA, 64);
                unsigned int a3 = __shfl(pk[2 * kk2 + 1][1], srcA, 64);
                unsigned int c0 = __shfl(pk[2 * kk2][0],     srcB, 64);
                unsigned int c1 = __shfl(pk[2 * kk2 + 1][0], srcB, 64);
                unsigned int c2 = __shfl(pk[2 * kk2][1],     srcB, 64);
                unsigned int c3 = __shfl(pk[2 * kk2 + 1][1], srcB, 64);
                uintx4 u;
                u[0] = hi2 ? a1 : a0;
                u[1] = hi2 ? a3 : a2;
                u[2] = hi2 ? c1 : c0;
                u[3] = hi2 ? c3 : c2;
                pb[t][kk2] = __builtin_bit_cast(short8, u);
            }
        }

        // O^T += V^T * P^T
#pragma unroll
        for (int kk2 = 0; kk2 < 2; kk2++) {
            const int pbv = ((kk2 * 4 + quad) ^ (l16 & 7)) * 8;
#pragma unroll
            for (int n = 0; n < 8; n++) {
                short8 vf = *(const short8*)(&lVc[(n * 16 + l16) * 64 + pbv]);
                o[0][n] = __builtin_amdgcn_mfma_f32_16x16x32_bf16(vf, pb[0][kk2], o[0][n], 0, 0, 0);
                o[1][n] = __builtin_amdgcn_mfma_f32_16x16x32_bf16(vf, pb[1][kk2], o[1][n], 0, 0, 0);
            }
        }

        cur ^= 1;
    }

    // final row-sum reduce across quads (once) -> reciprocal
    float inv[2];
#pragma unroll
    for (int t = 0; t < 2; t++) {
        float s = lsum[t];
        s += __shfl_xor(s, 16, 64);
        s += __shfl_xor(s, 32, 64);
        inv[t] = 1.0f / s;
    }

    // O^T epilogue: lane l16 = q (token), rows d = n*16 + quad*4 + r
#pragma unroll
    for (int t = 0; t < 2; t++) {
        const int row = qt * 128 + wave * 32 + t * 16 + l16;
        const size_t tok = (size_t)(b * 2048 + row);
        short* outp = (short*)attn_out + tok * 4096 + h * 128 + quad * 4;
#pragma unroll
        for (int n = 0; n < 8; n++) {
            short4v s4;
#pragma unroll
            for (int r = 0; r < 4; r++) s4[r] = bf16bits(o[t][n][r] * inv[t]);
            *(short4v*)(outp + n * 16) = s4;
        }
    }
}

// ---------------------------------------------------------------------------
extern "C" void kernel_launch(void* const* d_in, const int* in_sizes, int n_in,
                              void* d_out, int out_size, void* d_ws, size_t ws_size,
                              hipStream_t stream) {
    const float* hidden = (const float*)d_in[0];
    const float* cosb   = (const float*)d_in[1];
    const float* sinb   = (const float*)d_in[2];
    const float* w_qkv  = (const float*)d_in[3];
    const float* w_o    = (const float*)d_in[4];
    const float* qw     = (const float*)d_in[5];
    const float* kw     = (const float*)d_in[6];

    char* ws = (char*)d_ws;
    __hip_bfloat16* qkv    = (__hip_bfloat16*)ws;                     // 50.33 MB
    __hip_bfloat16* attn_o = (__hip_bfloat16*)(ws + 50331648);        // 33.55 MB
    __hip_bfloat16* hb  = (__hip_bfloat16*)(ws + 83886080);           // 33.55 MB
    __hip_bfloat16* wb1 = (__hip_bfloat16*)(ws + 117440512);          // 50.33 MB
    __hip_bfloat16* wb2 = (__hip_bfloat16*)(ws + 167772160);          // 33.55 MB
    const size_t WS_FAST = 201326592;                                  // 192 MiB

    __hip_bfloat16* Vt = (__hip_bfloat16*)d_out;   // 8.4 MB scratch, dead before gemm2
    float* outp        = (float*)d_out;

    const bool fast = (ws_size >= WS_FAST);

    if (fast) {
        cvt_bf16<<<16777216 / 8 / 256, 256, 0, stream>>>(hidden, hb);
        cvt_bf16<<<25165824 / 8 / 256, 256, 0, stream>>>(w_qkv, wb1);
        cvt_bf16<<<16777216 / 8 / 256, 256, 0, stream>>>(w_o, wb2);
        // 4096x6144: 128x128 @ 4 waves, 64KB LDS -> 2 blocks/CU, 1536 blocks
        // = 6 exact chip-rounds; cross-block overlap hides barrier stalls.
        gemm_bt_dbuf<__hip_bfloat16, 128, 128, 256, 2><<<1536, 256, 0, stream>>>(
            hb, wb1, qkv, 4096, 6144, 4096);
    } else {
        dim3 g1(32, 48);
        gemm_bt_slow<true, __hip_bfloat16><<<g1, 256, 0, stream>>>(hidden, w_qkv, qkv, 4096, 6144, 4096);
    }

    rope_norm<<<40960, 256, 0, stream>>>(qkv, cosb, sinb, qw, kw);

    vtrans<<<512, 256, 0, stream>>>(qkv, Vt);

    attn_kernel<<<1024, 256, 0, stream>>>(qkv, Vt, attn_o);

    if (fast) {
        // 4096x4096: proven 256x256 @ 8 waves -> 256 blocks = 1 chip-wave
        gemm_bt_dbuf<float, 256, 256, 512, 4><<<256, 512, 0, stream>>>(
            attn_o, wb2, outp, 4096, 4096, 4096);
    } else {
        dim3 g2(32, 32);
        gemm_bt_slow<false, float><<<g2, 256, 0, stream>>>(attn_o, w_o, outp, 4096, 4096, 4096);
    }
}